// Round 4
// baseline (199.107 us; speedup 1.0000x reference)
//
#include <hip/hip_runtime.h>
#include <hip/hip_bf16.h>

typedef __bf16 bf16;
typedef __bf16 bf16x8 __attribute__((ext_vector_type(8)));
typedef float f32x4 __attribute__((ext_vector_type(4)));

#define EMB 768
#define NH 12
#define HD 64
#define SEQ 2048
#define NBATCH 2
#define NREL (2 * SEQ - 1)

// XOR-swizzle for 128B-row-stride LDS tiles (bits 9:7 -> 6:4). Involution.
__device__ __forceinline__ int swz(int bo) { return bo ^ ((bo >> 3) & 0x70); }

// global -> LDS async 16B copy (wave-uniform LDS base, lane i at +i*16).
typedef __attribute__((address_space(3))) unsigned int lds_u32;
typedef __attribute__((address_space(1))) unsigned int glb_u32;
__device__ __forceinline__ void gld16(const void* g, void* l) {
  __builtin_amdgcn_global_load_lds((const glb_u32*)g, (lds_u32*)l, 16, 0, 0);
}

// ---------------- bias bucket table: bias_tab[h][rel + 2047] ----------------
__global__ void k_bias_table(const float* __restrict__ rel_bias,
                             float* __restrict__ bias_tab) {
  int i = blockIdx.x * 256 + threadIdx.x;
  if (i >= NREL) return;
  int rel = i - (SEQ - 1);            // rel = s - t
  int bkt = (rel > 0) ? 16 : 0;
  int rp = rel < 0 ? -rel : rel;
  if (rp < 8) {
    bkt += rp;
  } else {
    float lf = (logf((float)rp * 0.125f) / 2.7725887222397811f) * 8.0f;
    int large = 8 + (int)lf;
    bkt += (large < 15) ? large : 15;
  }
  for (int h = 0; h < NH; ++h)
    bias_tab[h * NREL + i] = rel_bias[bkt * NH + h];
}

// ---------------- mask bits: mbits[b*32 + w] bit s = mask[b][w*64+s] --------
__global__ void k_maskbits(const unsigned char* __restrict__ mask,
                           unsigned long long* __restrict__ mbits) {
  int i = threadIdx.x;                // 64 words = NBATCH * (SEQ/64)
  int b = i >> 5, wd = i & 31;
  unsigned long long v = 0;
  for (int j = 0; j < 64; ++j)
    v |= (unsigned long long)(mask[b * SEQ + wd * 64 + j] != 0) << j;
  mbits[i] = v;
}

// ------- W convert+transpose: W[k][n] f32 -> Wt[n][k] bf16 (z: q,k,v,o) -----
__global__ __launch_bounds__(256) void k_cvt_w(
    const float* __restrict__ Wq, const float* __restrict__ Wk,
    const float* __restrict__ Wv, const float* __restrict__ Wo,
    bf16* __restrict__ Wt3, bf16* __restrict__ Wto) {
  const int z = blockIdx.z;
  const float* W = z == 0 ? Wq : z == 1 ? Wk : z == 2 ? Wv : Wo;
  bf16* O = z < 3 ? Wt3 + (size_t)z * EMB * EMB : Wto;
  int n = blockIdx.y * 64 + (threadIdx.x >> 2);
  int ks = blockIdx.x * 64 + (threadIdx.x & 3) * 16;
  union { bf16 e[16]; uint4 u[2]; } pk;
#pragma unroll
  for (int j = 0; j < 16; ++j)
    pk.e[j] = (bf16)W[(size_t)(ks + j) * EMB + n];
  *(uint4*)(O + (size_t)n * EMB + ks) = pk.u[0];
  *(uint4*)(O + (size_t)n * EMB + ks + 8) = pk.u[1];
}

// ---- QKV projection GEMM: 128x128 tile, BK=64 (m97 structure) --------------
__global__ __launch_bounds__(256) void k_proj_qkv(
    const float* __restrict__ Xq, const float* __restrict__ Xk,
    const float* __restrict__ Xv, const bf16* __restrict__ Wt3,
    const float* __restrict__ bq, const float* __restrict__ bk,
    const float* __restrict__ bv, bf16* __restrict__ oq,
    bf16* __restrict__ ok, bf16* __restrict__ ov) {
  __shared__ __align__(16) bf16 As[128 * 64];   // [m][k] linear
  __shared__ __align__(16) bf16 Bs[128 * 64];   // [n][k] linear
  const int z = blockIdx.z;
  const float* X = z == 0 ? Xq : z == 1 ? Xk : Xv;
  const bf16* Wt = Wt3 + (size_t)z * EMB * EMB;
  const float* bias = z == 0 ? bq : z == 1 ? bk : bv;
  bf16* C = z == 0 ? oq : z == 1 ? ok : ov;
  const float scale = z == 0 ? 0.125f : 1.0f;

  const int m0 = blockIdx.x * 128, n0 = blockIdx.y * 128;
  const int tid = threadIdx.x, lane = tid & 63, w = tid >> 6;
  const int c = lane & 15, g = lane >> 4;
  const int mo = (w >> 1) * 64, no = (w & 1) * 64;

  f32x4 acc[4][4] = {};
  for (int k0 = 0; k0 < EMB; k0 += 64) {
    __syncthreads();
#pragma unroll
    for (int jj = 0; jj < 4; ++jj) {
      int r = w * 32 + jj * 8 + (lane >> 3);
      gld16(Wt + (size_t)(n0 + r) * EMB + k0 + (lane & 7) * 8,
            (char*)Bs + (w * 32 + jj * 8) * 128);
    }
#pragma unroll
    for (int j = 0; j < 4; ++j) {
      int row = (tid >> 3) + j * 32;
      const float* ap = X + (size_t)(m0 + row) * EMB + k0 + (tid & 7) * 8;
      float4 f0 = *(const float4*)ap, f1 = *(const float4*)(ap + 4);
      bf16x8 hh;
      hh[0] = (bf16)f0.x; hh[1] = (bf16)f0.y; hh[2] = (bf16)f0.z; hh[3] = (bf16)f0.w;
      hh[4] = (bf16)f1.x; hh[5] = (bf16)f1.y; hh[6] = (bf16)f1.z; hh[7] = (bf16)f1.w;
      *(bf16x8*)((char*)As + tid * 16 + j * 4096) = hh;
    }
    __syncthreads();
#pragma unroll
    for (int kk = 0; kk < 2; ++kk) {
      bf16x8 av[4], bvf[4];
#pragma unroll
      for (int mf = 0; mf < 4; ++mf)
        av[mf] = *(const bf16x8*)((char*)As + (mo + mf * 16 + c) * 128 + kk * 64 + g * 16);
#pragma unroll
      for (int nf = 0; nf < 4; ++nf)
        bvf[nf] = *(const bf16x8*)((char*)Bs + (no + nf * 16 + c) * 128 + kk * 64 + g * 16);
#pragma unroll
      for (int mf = 0; mf < 4; ++mf)
#pragma unroll
        for (int nf = 0; nf < 4; ++nf)
          acc[mf][nf] = __builtin_amdgcn_mfma_f32_16x16x32_bf16(bvf[nf], av[mf], acc[mf][nf], 0, 0, 0);
    }
  }
#pragma unroll
  for (int nf = 0; nf < 4; ++nf) {
    int n = n0 + no + nf * 16 + g * 4;
    float4 b4 = *(const float4*)&bias[n];
#pragma unroll
    for (int mf = 0; mf < 4; ++mf) {
      int m = m0 + mo + mf * 16 + c;
      union { bf16 e[4]; uint2 u; } pk;
      pk.e[0] = (bf16)((acc[mf][nf][0] + b4.x) * scale);
      pk.e[1] = (bf16)((acc[mf][nf][1] + b4.y) * scale);
      pk.e[2] = (bf16)((acc[mf][nf][2] + b4.z) * scale);
      pk.e[3] = (bf16)((acc[mf][nf][3] + b4.w) * scale);
      *(uint2*)(C + (size_t)m * EMB + n) = pk.u;
    }
  }
}

// ---- output projection: bf16 A[4096][768] @ Wto[n][k] + bo -> f32 ----------
__global__ __launch_bounds__(256) void k_proj_out(
    const bf16* __restrict__ A, const bf16* __restrict__ Wt,
    const float* __restrict__ bias, float* __restrict__ out) {
  __shared__ __align__(16) bf16 As[128 * 64];
  __shared__ __align__(16) bf16 Bs[128 * 64];
  const int m0 = blockIdx.x * 128, n0 = blockIdx.y * 128;
  const int tid = threadIdx.x, lane = tid & 63, w = tid >> 6;
  const int c = lane & 15, g = lane >> 4;
  const int mo = (w >> 1) * 64, no = (w & 1) * 64;
  f32x4 acc[4][4] = {};
  for (int k0 = 0; k0 < EMB; k0 += 64) {
    __syncthreads();
#pragma unroll
    for (int jj = 0; jj < 4; ++jj) {
      int r = w * 32 + jj * 8 + (lane >> 3);
      gld16(A + (size_t)(m0 + r) * EMB + k0 + (lane & 7) * 8,
            (char*)As + (w * 32 + jj * 8) * 128);
      gld16(Wt + (size_t)(n0 + r) * EMB + k0 + (lane & 7) * 8,
            (char*)Bs + (w * 32 + jj * 8) * 128);
    }
    __syncthreads();
#pragma unroll
    for (int kk = 0; kk < 2; ++kk) {
      bf16x8 av[4], bvf[4];
#pragma unroll
      for (int mf = 0; mf < 4; ++mf)
        av[mf] = *(const bf16x8*)((char*)As + (mo + mf * 16 + c) * 128 + kk * 64 + g * 16);
#pragma unroll
      for (int nf = 0; nf < 4; ++nf)
        bvf[nf] = *(const bf16x8*)((char*)Bs + (no + nf * 16 + c) * 128 + kk * 64 + g * 16);
#pragma unroll
      for (int mf = 0; mf < 4; ++mf)
#pragma unroll
        for (int nf = 0; nf < 4; ++nf)
          acc[mf][nf] = __builtin_amdgcn_mfma_f32_16x16x32_bf16(bvf[nf], av[mf], acc[mf][nf], 0, 0, 0);
    }
  }
#pragma unroll
  for (int nf = 0; nf < 4; ++nf) {
    int n = n0 + no + nf * 16 + g * 4;
    float4 b4 = *(const float4*)&bias[n];
#pragma unroll
    for (int mf = 0; mf < 4; ++mf) {
      int m = m0 + mo + mf * 16 + c;
      float4 v;
      v.x = acc[mf][nf][0] + b4.x;
      v.y = acc[mf][nf][1] + b4.y;
      v.z = acc[mf][nf][2] + b4.z;
      v.w = acc[mf][nf][3] + b4.w;
      *(float4*)(out + (size_t)m * EMB + n) = v;
    }
  }
}

// ---- V transpose: vb[4096][768] -> vt[B*H][64][2048] -----------------------
__global__ __launch_bounds__(256) void k_tr_v(const bf16* __restrict__ vb,
                                              bf16* __restrict__ vt) {
  __shared__ __align__(16) bf16 T[64 * 64];  // [s][d] swizzled
  const int bh = blockIdx.x;
  const int b = bh / NH, h = bh % NH;
  const int s0 = blockIdx.y * 64;
  const int tid = threadIdx.x;
#pragma unroll
  for (int ii = 0; ii < 2; ++ii) {
    int i = tid * 2 + ii;
    int s = i >> 3, c16 = i & 7;
    uint4 v = *(const uint4*)(vb + (size_t)((s0 + s) * NBATCH + b) * EMB + h * 64 + c16 * 8);
    *(uint4*)((char*)T + swz(s * 128 + c16 * 16)) = v;
  }
  __syncthreads();
#pragma unroll
  for (int jj = 0; jj < 2; ++jj) {
    int j = tid * 2 + jj;
    int d = j >> 3, sc = (j & 7) * 8;
    union { bf16 e[8]; uint4 u; } pk;
#pragma unroll
    for (int q = 0; q < 8; ++q)
      pk.e[q] = *(const bf16*)((char*)T + swz((sc + q) * 128 + d * 2));
    *(uint4*)(vt + ((size_t)bh * 64 + d) * SEQ + s0 + sc) = pk.u;
  }
}

// ----------------------------- flash attention ------------------------------
// Swapped QK^T + in-register softmax. This round: const-bias fast path,
// u64 mask bits, defer-max (THR=8), T14 reg-dbuf staging, T5 setprio.
__global__ __launch_bounds__(256) void k_attn(
    const bf16* __restrict__ qb, const bf16* __restrict__ kb,
    const bf16* __restrict__ vtg, const unsigned long long* __restrict__ mbits,
    const float* __restrict__ bias_tab, bf16* __restrict__ attn_out) {
  __shared__ __align__(16) bf16 Ks[64 * 64];   // [pos(s)][d]  swizzled
  __shared__ __align__(16) bf16 Vt[64 * 64];   // [d][s]       swizzled
  __shared__ float bloc[128];
  const int bh = blockIdx.x;
  const int b = bh / NH, h = bh % NH;
  const int t0 = blockIdx.y * 64;
  const int tid = threadIdx.x;
  const int lane = tid & 63, w = tid >> 6;
  const int c = lane & 15, g = lane >> 4;
  const float NEGINF = -__builtin_inff();
  const int tl = w * 16 + c;                   // this lane's t (block-local)

  bf16x8 qf[2];
  {
    const bf16* qp = qb + (size_t)((t0 + tl) * NBATCH + b) * EMB + h * 64 + g * 8;
    qf[0] = *(const bf16x8*)qp;
    qf[1] = *(const bf16x8*)(qp + 32);
  }
  const float* btab = bias_tab + h * NREL + (SEQ - 1);
  const float cpos = btab[SEQ - 1];            // bucket 31 (rel >= 128)
  const float cneg = btab[-(SEQ - 1)];         // bucket 15 (rel <= -128)

  // staging geometry: element i = tid + j*256; s(d) = i>>3, col16 = i&7
  const int si = tid >> 3, c16 = tid & 7;
  const bf16* kbase = kb + (size_t)b * EMB + h * 64 + c16 * 8;
  const bf16* vbase = vtg + (size_t)bh * HD * SEQ + c16 * 8;
  uint4 kreg[2], vreg[2];
  float breg = 0.f;

#define STAGE_LOAD(IT) {                                                      \
    int s0n = (IT) * 64;                                                      \
    _Pragma("unroll") for (int j = 0; j < 2; ++j) {                           \
      kreg[j] = *(const uint4*)(kbase + (size_t)(s0n + si + j * 32) * (NBATCH * EMB)); \
      vreg[j] = *(const uint4*)(vbase + (size_t)(si + j * 32) * SEQ + s0n);   \
    }                                                                         \
    int dn = s0n - t0;                                                        \
    if (dn > -192 && dn < 192 && tid < 127) breg = btab[dn + tid - 63];       \
  }

#define STAGE_WRITE(IT) {                                                     \
    _Pragma("unroll") for (int j = 0; j < 2; ++j) {                           \
      int s = si + j * 32;                                                    \
      int pos = (s & 0x23) | ((s & 0x04) << 2) | ((s & 0x18) >> 1);           \
      *(uint4*)((char*)Ks + swz(pos * 128 + c16 * 16)) = kreg[j];             \
      *(uint4*)((char*)Vt + swz(s * 128 + c16 * 16)) = vreg[j];               \
    }                                                                         \
    int dn = (IT) * 64 - t0;                                                  \
    if (dn > -192 && dn < 192 && tid < 127) bloc[tid] = breg;                 \
  }

  float m_p = -1e30f, l_p = 0.f;
  f32x4 o[4] = {};

  STAGE_LOAD(0);
  STAGE_WRITE(0);
  __syncthreads();

  for (int it = 0; it < SEQ / 64; ++it) {
    const int s0 = it * 64;
    if (it < SEQ / 64 - 1) STAGE_LOAD(it + 1);     // T14: issue early
    const unsigned long long mb = mbits[b * 32 + it];

    // QK^T (swapped): sacc[nf][r] = S_raw[t][s0 + 32*(nf>>1)+g*8+(nf&1)*4+r]
    f32x4 sacc[4] = {};
    __builtin_amdgcn_s_setprio(1);
#pragma unroll
    for (int kk = 0; kk < 2; ++kk) {
#pragma unroll
      for (int nf = 0; nf < 4; ++nf) {
        bf16x8 kf = *(const bf16x8*)((char*)Ks + swz((nf * 16 + c) * 128 + kk * 64 + g * 16));
        sacc[nf] = __builtin_amdgcn_mfma_f32_16x16x32_bf16(kf, qf[kk], sacc[nf], 0, 0, 0);
      }
    }
    __builtin_amdgcn_s_setprio(0);

    const int d = s0 - t0;
    const bool slow = (d > -192) && (d < 192);
    const float cb = slow ? 0.f : (d >= 192 ? cpos : cneg);

    // bias (slow path only) + mask + row max
    float rmax = NEGINF;
#pragma unroll
    for (int nf = 0; nf < 4; ++nf) {
      int sb = 32 * (nf >> 1) + g * 8 + (nf & 1) * 4;
#pragma unroll
      for (int r = 0; r < 4; ++r) {
        float v = sacc[nf][r];
        if (slow) v += bloc[sb + r - tl + 63];
        sacc[nf][r] = v;
      }
    }
    if (mb) {
#pragma unroll
      for (int nf = 0; nf < 4; ++nf) {
        int sb = 32 * (nf >> 1) + g * 8 + (nf & 1) * 4;
#pragma unroll
        for (int r = 0; r < 4; ++r)
          if ((mb >> (sb + r)) & 1) sacc[nf][r] = NEGINF;
      }
    }
#pragma unroll
    for (int nf = 0; nf < 4; ++nf)
#pragma unroll
      for (int r = 0; r < 4; ++r) rmax = fmaxf(rmax, sacc[nf][r]);
    rmax = fmaxf(rmax, __shfl_xor(rmax, 16, 64));
    rmax = fmaxf(rmax, __shfl_xor(rmax, 32, 64));
    const float rm = rmax + cb;                   // row max in score space

    // defer-max: only rescale when some row grew past m_p + 8
    if (!__all(rm <= m_p + 8.0f)) {
      float m_new = fmaxf(m_p, rm);
      float scl = __expf(m_p - m_new);
      m_p = m_new;
      l_p *= scl;
#pragma unroll
      for (int r = 0; r < 4; ++r) {
        float so = __shfl(scl, g * 4 + r, 64);
#pragma unroll
        for (int nf2 = 0; nf2 < 4; ++nf2) o[nf2][r] *= so;
      }
    }
    const float msh = m_p - cb;
    float rsum = 0.f;
    bf16x8 pa[2];
#pragma unroll
    for (int kk = 0; kk < 2; ++kk)
#pragma unroll
      for (int j = 0; j < 8; ++j) {
        float e = __expf(sacc[2 * kk + (j >> 2)][j & 3] - msh);
        rsum += e;
        pa[kk][j] = (bf16)e;
      }
    rsum += __shfl_xor(rsum, 16, 64);
    rsum += __shfl_xor(rsum, 32, 64);
    l_p += rsum;

    // PV
    __builtin_amdgcn_s_setprio(1);
#pragma unroll
    for (int kk = 0; kk < 2; ++kk) {
#pragma unroll
      for (int nf2 = 0; nf2 < 4; ++nf2) {
        bf16x8 vbf = *(const bf16x8*)((char*)Vt + swz((nf2 * 16 + c) * 128 + kk * 64 + g * 16));
        o[nf2] = __builtin_amdgcn_mfma_f32_16x16x32_bf16(pa[kk], vbf, o[nf2], 0, 0, 0);
      }
    }
    __builtin_amdgcn_s_setprio(0);

    if (it < SEQ / 64 - 1) {
      __syncthreads();            // all waves done reading tile it
      STAGE_WRITE(it + 1);        // write prefetched tile (vmcnt via reg dep)
      __syncthreads();
    }
  }
  // epilogue: O rows t = t0 + w*16 + g*4 + r; l lives at lane c'=g*4+r
#pragma unroll
  for (int r = 0; r < 4; ++r) {
    float lo = __shfl(l_p, g * 4 + r, 64);
    float inv = 1.0f / lo;
    int t = t0 + w * 16 + g * 4 + r;
#pragma unroll
    for (int nf2 = 0; nf2 < 4; ++nf2) {
      int dd = nf2 * 16 + c;
      attn_out[((size_t)t * NBATCH + b) * EMB + h * HD + dd] = (bf16)(o[nf2][r] * inv);
    }
  }
#undef STAGE_LOAD
#undef STAGE_WRITE
}

extern "C" void kernel_launch(void* const* d_in, const int* in_sizes, int n_in,
                              void* d_out, int out_size, void* d_ws, size_t ws_size,
                              hipStream_t stream) {
  const float* query = (const float*)d_in[0];
  const float* key_ = (const float*)d_in[1];
  const float* value = (const float*)d_in[2];
  const unsigned char* kpm = (const unsigned char*)d_in[3];
  const float* Wq = (const float*)d_in[4];
  const float* bq = (const float*)d_in[5];
  const float* Wk = (const float*)d_in[6];
  const float* bk = (const float*)d_in[7];
  const float* Wv = (const float*)d_in[8];
  const float* bv = (const float*)d_in[9];
  const float* Wo = (const float*)d_in[10];
  const float* bo = (const float*)d_in[11];
  const float* rel_bias = (const float*)d_in[12];
  float* out = (float*)d_out;

  char* ws = (char*)d_ws;
  const size_t SZb = (size_t)SEQ * NBATCH * EMB * sizeof(bf16);  // 6.29 MB
  const size_t WSZ = (size_t)EMB * EMB * sizeof(bf16);           // 1.18 MB
  bf16* qbb = (bf16*)(ws);
  bf16* kbb = (bf16*)(ws + SZb);
  bf16* vbb = (bf16*)(ws + 2 * SZb);
  bf16* vtb = (bf16*)(ws + 3 * SZb);
  bf16* attnb = vbb;                       // vb dead after k_tr_v
  bf16* Wt3 = (bf16*)(ws + 4 * SZb);
  bf16* Wto = (bf16*)(ws + 4 * SZb + 3 * WSZ);
  float* bias_tab = (float*)(ws + 4 * SZb + 4 * WSZ);
  unsigned long long* mbits =
      (unsigned long long*)(ws + 4 * SZb + 4 * WSZ + (size_t)NH * NREL * sizeof(float) + 64);

  k_bias_table<<<16, 256, 0, stream>>>(rel_bias, bias_tab);
  k_maskbits<<<1, 64, 0, stream>>>(kpm, mbits);
  k_cvt_w<<<dim3(12, 12, 4), 256, 0, stream>>>(Wq, Wk, Wv, Wo, Wt3, Wto);
  k_proj_qkv<<<dim3(32, 6, 3), 256, 0, stream>>>(
      query, key_, value, Wt3, bq, bk, bv, qbb, kbb, vbb);
  k_tr_v<<<dim3(NBATCH * NH, SEQ / 64), 256, 0, stream>>>(vbb, vtb);
  k_attn<<<dim3(NBATCH * NH, SEQ / 64), 256, 0, stream>>>(qbb, kbb, vtb, mbits, bias_tab, attnb);
  k_proj_out<<<dim3(32, 6), 256, 0, stream>>>(attnb, Wto, bo, out);
}

// Round 5
// 148.441 us; speedup vs baseline: 1.3413x; 1.3413x over previous
//
#include <hip/hip_runtime.h>
#include <hip/hip_bf16.h>

typedef __bf16 bf16;
typedef __bf16 bf16x8 __attribute__((ext_vector_type(8)));
typedef float f32x4 __attribute__((ext_vector_type(4)));

#define EMB 768
#define NH 12
#define HD 64
#define SEQ 2048
#define NBATCH 2
#define NREL (2 * SEQ - 1)

// XOR-swizzle for 128B-row-stride LDS tiles (bits 9:7 -> 6:4). Involution.
__device__ __forceinline__ int swz(int bo) { return bo ^ ((bo >> 3) & 0x70); }
// K-row permutation making PV A-fragments lane-local (verified r2-r4).
__device__ __forceinline__ int kpos(int s) {
  return (s & 0x23) | ((s & 0x04) << 2) | ((s & 0x18) >> 1);
}

// global -> LDS async 16B copy (wave-uniform LDS base, lane i at +i*16).
typedef __attribute__((address_space(3))) unsigned int lds_u32;
typedef __attribute__((address_space(1))) unsigned int glb_u32;
__device__ __forceinline__ void gld16(const void* g, void* l) {
  __builtin_amdgcn_global_load_lds((const glb_u32*)g, (lds_u32*)l, 16, 0, 0);
}

// ---------------- bias bucket table: bias_tab[h][rel + 2047] ----------------
__global__ void k_bias_table(const float* __restrict__ rel_bias,
                             float* __restrict__ bias_tab) {
  int i = blockIdx.x * 256 + threadIdx.x;
  if (i >= NREL) return;
  int rel = i - (SEQ - 1);            // rel = s - t
  int bkt = (rel > 0) ? 16 : 0;
  int rp = rel < 0 ? -rel : rel;
  if (rp < 8) {
    bkt += rp;
  } else {
    float lf = (logf((float)rp * 0.125f) / 2.7725887222397811f) * 8.0f;
    int large = 8 + (int)lf;
    bkt += (large < 15) ? large : 15;
  }
  for (int h = 0; h < NH; ++h)
    bias_tab[h * NREL + i] = rel_bias[bkt * NH + h];
}

// ---------------- mask bits: mbits[b*32 + w] bit s = mask[b][w*64+s] --------
__global__ void k_maskbits(const unsigned char* __restrict__ mask,
                           unsigned long long* __restrict__ mbits) {
  int i = threadIdx.x;                // 64 words = NBATCH * (SEQ/64)
  int b = i >> 5, wd = i & 31;
  unsigned long long v = 0;
  for (int j = 0; j < 64; ++j)
    v |= (unsigned long long)(mask[b * SEQ + wd * 64 + j] != 0) << j;
  mbits[i] = v;
}

// ------- W convert+transpose: W[k][n] f32 -> Wt[n][k] bf16 (z: q,k,v,o) -----
__global__ __launch_bounds__(256) void k_cvt_w(
    const float* __restrict__ Wq, const float* __restrict__ Wk,
    const float* __restrict__ Wv, const float* __restrict__ Wo,
    bf16* __restrict__ Wt3, bf16* __restrict__ Wto) {
  const int z = blockIdx.z;
  const float* W = z == 0 ? Wq : z == 1 ? Wk : z == 2 ? Wv : Wo;
  bf16* O = z < 3 ? Wt3 + (size_t)z * EMB * EMB : Wto;
  int n = blockIdx.y * 64 + (threadIdx.x >> 2);
  int ks = blockIdx.x * 64 + (threadIdx.x & 3) * 16;
  union { bf16 e[16]; uint4 u[2]; } pk;
#pragma unroll
  for (int j = 0; j < 16; ++j)
    pk.e[j] = (bf16)W[(size_t)(ks + j) * EMB + n];
  *(uint4*)(O + (size_t)n * EMB + ks) = pk.u[0];
  *(uint4*)(O + (size_t)n * EMB + ks + 8) = pk.u[1];
}

// ---- QKV projection GEMM: 128x128 tile, BK=64 (m97 structure) --------------
// z=0: Q scaled -> row-major.  z=1: K -> pre-swizzled tile image gk.
// z=2: V -> row-major (repacked by k_repack_v).
__global__ __launch_bounds__(256) void k_proj_qkv(
    const float* __restrict__ Xq, const float* __restrict__ Xk,
    const float* __restrict__ Xv, const bf16* __restrict__ Wt3,
    const float* __restrict__ bq, const float* __restrict__ bk,
    const float* __restrict__ bv, bf16* __restrict__ oq,
    bf16* __restrict__ gk, bf16* __restrict__ ov) {
  __shared__ __align__(16) bf16 As[128 * 64];   // [m][k] linear
  __shared__ __align__(16) bf16 Bs[128 * 64];   // [n][k] linear
  const int z = blockIdx.z;
  const float* X = z == 0 ? Xq : z == 1 ? Xk : Xv;
  const bf16* Wt = Wt3 + (size_t)z * EMB * EMB;
  const float* bias = z == 0 ? bq : z == 1 ? bk : bv;
  bf16* C = z == 0 ? oq : ov;
  const float scale = z == 0 ? 0.125f : 1.0f;

  const int m0 = blockIdx.x * 128, n0 = blockIdx.y * 128;
  const int tid = threadIdx.x, lane = tid & 63, w = tid >> 6;
  const int c = lane & 15, g = lane >> 4;
  const int mo = (w >> 1) * 64, no = (w & 1) * 64;

  f32x4 acc[4][4] = {};
  for (int k0 = 0; k0 < EMB; k0 += 64) {
    __syncthreads();
#pragma unroll
    for (int jj = 0; jj < 4; ++jj) {
      gld16(Wt + (size_t)(n0 + w * 32 + jj * 8 + (lane >> 3)) * EMB + k0 + (lane & 7) * 8,
            (char*)Bs + (w * 32 + jj * 8) * 128);
    }
#pragma unroll
    for (int j = 0; j < 4; ++j) {
      int row = (tid >> 3) + j * 32;
      const float* ap = X + (size_t)(m0 + row) * EMB + k0 + (tid & 7) * 8;
      float4 f0 = *(const float4*)ap, f1 = *(const float4*)(ap + 4);
      bf16x8 hh;
      hh[0] = (bf16)f0.x; hh[1] = (bf16)f0.y; hh[2] = (bf16)f0.z; hh[3] = (bf16)f0.w;
      hh[4] = (bf16)f1.x; hh[5] = (bf16)f1.y; hh[6] = (bf16)f1.z; hh[7] = (bf16)f1.w;
      *(bf16x8*)((char*)As + tid * 16 + j * 4096) = hh;
    }
    __syncthreads();
#pragma unroll
    for (int kk = 0; kk < 2; ++kk) {
      bf16x8 av[4], bvf[4];
#pragma unroll
      for (int mf = 0; mf < 4; ++mf)
        av[mf] = *(const bf16x8*)((char*)As + (mo + mf * 16 + c) * 128 + kk * 64 + g * 16);
#pragma unroll
      for (int nf = 0; nf < 4; ++nf)
        bvf[nf] = *(const bf16x8*)((char*)Bs + (no + nf * 16 + c) * 128 + kk * 64 + g * 16);
#pragma unroll
      for (int mf = 0; mf < 4; ++mf)
#pragma unroll
        for (int nf = 0; nf < 4; ++nf)
          acc[mf][nf] = __builtin_amdgcn_mfma_f32_16x16x32_bf16(bvf[nf], av[mf], acc[mf][nf], 0, 0, 0);
    }
  }
#pragma unroll
  for (int nf = 0; nf < 4; ++nf) {
    int n = n0 + no + nf * 16 + g * 4;
    float4 b4 = *(const float4*)&bias[n];
#pragma unroll
    for (int mf = 0; mf < 4; ++mf) {
      int m = m0 + mo + mf * 16 + c;
      union { bf16 e[4]; uint2 u; } pk;
      pk.e[0] = (bf16)((acc[mf][nf][0] + b4.x) * scale);
      pk.e[1] = (bf16)((acc[mf][nf][1] + b4.y) * scale);
      pk.e[2] = (bf16)((acc[mf][nf][2] + b4.z) * scale);
      pk.e[3] = (bf16)((acc[mf][nf][3] + b4.w) * scale);
      if (z == 1) {          // K tile image: byte swz(kpos(s)*128 + slot) = K[s]
        int t = m >> 1, bb = m & 1;
        int hh = n >> 6, d = n & 63;
        char* base = (char*)gk + ((size_t)(bb * NH + hh) * 32 + (t >> 6)) * 8192;
        *(uint2*)(base + swz(kpos(t & 63) * 128 + (d & ~7) * 2) + (d & 4) * 2) = pk.u;
      } else {
        *(uint2*)(C + (size_t)m * EMB + n) = pk.u;
      }
    }
  }
}

// ---- output projection: bf16 A[4096][768] @ Wto[n][k] + bo -> f32 ----------
__global__ __launch_bounds__(256) void k_proj_out(
    const bf16* __restrict__ A, const bf16* __restrict__ Wt,
    const float* __restrict__ bias, float* __restrict__ out) {
  __shared__ __align__(16) bf16 As[128 * 64];
  __shared__ __align__(16) bf16 Bs[128 * 64];
  const int m0 = blockIdx.x * 128, n0 = blockIdx.y * 128;
  const int tid = threadIdx.x, lane = tid & 63, w = tid >> 6;
  const int c = lane & 15, g = lane >> 4;
  const int mo = (w >> 1) * 64, no = (w & 1) * 64;
  f32x4 acc[4][4] = {};
  for (int k0 = 0; k0 < EMB; k0 += 64) {
    __syncthreads();
#pragma unroll
    for (int jj = 0; jj < 4; ++jj) {
      int r = w * 32 + jj * 8 + (lane >> 3);
      gld16(A + (size_t)(m0 + r) * EMB + k0 + (lane & 7) * 8,
            (char*)As + (w * 32 + jj * 8) * 128);
      gld16(Wt + (size_t)(n0 + r) * EMB + k0 + (lane & 7) * 8,
            (char*)Bs + (w * 32 + jj * 8) * 128);
    }
    __syncthreads();
#pragma unroll
    for (int kk = 0; kk < 2; ++kk) {
      bf16x8 av[4], bvf[4];
#pragma unroll
      for (int mf = 0; mf < 4; ++mf)
        av[mf] = *(const bf16x8*)((char*)As + (mo + mf * 16 + c) * 128 + kk * 64 + g * 16);
#pragma unroll
      for (int nf = 0; nf < 4; ++nf)
        bvf[nf] = *(const bf16x8*)((char*)Bs + (no + nf * 16 + c) * 128 + kk * 64 + g * 16);
#pragma unroll
      for (int mf = 0; mf < 4; ++mf)
#pragma unroll
        for (int nf = 0; nf < 4; ++nf)
          acc[mf][nf] = __builtin_amdgcn_mfma_f32_16x16x32_bf16(bvf[nf], av[mf], acc[mf][nf], 0, 0, 0);
    }
  }
#pragma unroll
  for (int nf = 0; nf < 4; ++nf) {
    int n = n0 + no + nf * 16 + g * 4;
    float4 b4 = *(const float4*)&bias[n];
#pragma unroll
    for (int mf = 0; mf < 4; ++mf) {
      int m = m0 + mo + mf * 16 + c;
      float4 v;
      v.x = acc[mf][nf][0] + b4.x;
      v.y = acc[mf][nf][1] + b4.y;
      v.z = acc[mf][nf][2] + b4.z;
      v.w = acc[mf][nf][3] + b4.w;
      *(float4*)(out + (size_t)m * EMB + n) = v;
    }
  }
}

// ---- V repack: vb row-major [4096][768] -> gv tile images ------------------
// image byte swz(d*128 + c16*16) = V^T[d][s0 + c16*8 .. +8]
__global__ __launch_bounds__(256) void k_repack_v(const bf16* __restrict__ vb,
                                                  bf16* __restrict__ gv) {
  __shared__ __align__(16) bf16 T[64 * 64];  // [s][d] swizzled
  const int bh = blockIdx.x;
  const int b = bh / NH, h = bh % NH;
  const int s0 = blockIdx.y * 64;
  const int tid = threadIdx.x;
#pragma unroll
  for (int ii = 0; ii < 2; ++ii) {
    int i = tid * 2 + ii;
    int s = i >> 3, c16 = i & 7;
    uint4 v = *(const uint4*)(vb + (size_t)((s0 + s) * NBATCH + b) * EMB + h * 64 + c16 * 8);
    *(uint4*)((char*)T + swz(s * 128 + c16 * 16)) = v;
  }
  __syncthreads();
  char* out = (char*)gv + ((size_t)bh * 32 + blockIdx.y) * 8192;
#pragma unroll
  for (int jj = 0; jj < 2; ++jj) {
    int j = tid * 2 + jj;
    int d = j >> 3, c16 = j & 7;
    union { bf16 e[8]; uint4 u; } pk;
#pragma unroll
    for (int q = 0; q < 8; ++q)
      pk.e[q] = *(const bf16*)((char*)T + swz((c16 * 8 + q) * 128 + d * 2));
    *(uint4*)(out + swz(d * 128 + c16 * 16)) = pk.u;
  }
}

// ----------------------------- flash attention ------------------------------
// Pre-packed K/V tile images + gld16 double-buffer pipeline (T3 2-phase),
// block-wide bias slab, maskbits, const-bias fast path, defer-max, setprio.
__global__ __launch_bounds__(256) void k_attn(
    const bf16* __restrict__ qb, const bf16* __restrict__ gk,
    const bf16* __restrict__ gv, const unsigned long long* __restrict__ mbits,
    const float* __restrict__ bias_tab, bf16* __restrict__ attn_out) {
  __shared__ __align__(16) bf16 KV[2][2][4096];  // [buf][K/V][8KB image]
  __shared__ float Ball[2112];                   // bias for all s, this t-block
  const int bh = blockIdx.x;
  const int b = bh / NH, h = bh % NH;
  const int t0 = blockIdx.y * 64;
  const int tid = threadIdx.x;
  const int lane = tid & 63, w = tid >> 6;
  const int c = lane & 15, g = lane >> 4;
  const float NEGINF = -__builtin_inff();
  const int tl = w * 16 + c;                   // this lane's t (block-local)

  const char* kimg = (const char*)gk + (size_t)bh * 32 * 8192;
  const char* vimg = (const char*)gv + (size_t)bh * 32 * 8192;

#define ISSUE(IT, BUF) do {                                                  \
    const char* ks_ = kimg + (size_t)(IT) * 8192;                            \
    const char* vs_ = vimg + (size_t)(IT) * 8192;                            \
    _Pragma("unroll") for (int jj = 0; jj < 2; ++jj) {                       \
      int ch = w * 2 + jj;                                                   \
      gld16(ks_ + ch * 1024 + lane * 16, (char*)KV[BUF][0] + ch * 1024);     \
      gld16(vs_ + ch * 1024 + lane * 16, (char*)KV[BUF][1] + ch * 1024);     \
    }                                                                        \
  } while (0)

  ISSUE(0, 0);
  // Q fragments (B operand), loop-invariant
  bf16x8 qf[2];
  {
    const bf16* qp = qb + (size_t)((t0 + tl) * NBATCH + b) * EMB + h * 64 + g * 8;
    qf[0] = *(const bf16x8*)qp;
    qf[1] = *(const bf16x8*)(qp + 32);
  }
  // bias slab: Ball[j] = btab[j - t0 - 63]; lookup idx = s - tl_local + 63
  const float* btab = bias_tab + h * NREL + (SEQ - 1);
  for (int j = tid; j < 2111; j += 256) Ball[j] = btab[j - t0 - 63];
  const float cpos = btab[SEQ - 1];            // bucket 31 (rel >= 128)
  const float cneg = btab[-(SEQ - 1)];         // bucket 15 (rel <= -128)

  float m_p = -1e30f, l_p = 0.f;
  f32x4 o[4] = {};

  asm volatile("s_waitcnt vmcnt(0)" ::: "memory");
  __syncthreads();

  for (int it = 0; it < SEQ / 64; ++it) {
    const int cur = it & 1;
    if (it < SEQ / 64 - 1) ISSUE(it + 1, cur ^ 1);
    const unsigned long long mb = mbits[b * 32 + it];
    const char* Ks = (const char*)KV[cur][0];
    const char* Vs = (const char*)KV[cur][1];

    // QK^T (swapped): sacc[nf][r] = S_raw[t0+tl][s0 + 32*(nf>>1)+g*8+(nf&1)*4+r]
    f32x4 sacc[4] = {};
    __builtin_amdgcn_s_setprio(1);
#pragma unroll
    for (int kk = 0; kk < 2; ++kk) {
#pragma unroll
      for (int nf = 0; nf < 4; ++nf) {
        bf16x8 kf = *(const bf16x8*)(Ks + swz((nf * 16 + c) * 128 + kk * 64 + g * 16));
        sacc[nf] = __builtin_amdgcn_mfma_f32_16x16x32_bf16(kf, qf[kk], sacc[nf], 0, 0, 0);
      }
    }
    __builtin_amdgcn_s_setprio(0);

    const int s0 = it * 64;
    const int d = s0 - t0;
    const bool slow = (d > -192) && (d < 192);
    const float cb = slow ? 0.f : (d >= 192 ? cpos : cneg);

    float rmax = NEGINF;
    if (slow) {
      const int bidx = s0 - tl + 63;
#pragma unroll
      for (int nf = 0; nf < 4; ++nf) {
        int sb = 32 * (nf >> 1) + g * 8 + (nf & 1) * 4;
#pragma unroll
        for (int r = 0; r < 4; ++r) sacc[nf][r] += Ball[bidx + sb + r];
      }
    }
    if (mb) {
#pragma unroll
      for (int nf = 0; nf < 4; ++nf) {
        int sb = 32 * (nf >> 1) + g * 8 + (nf & 1) * 4;
#pragma unroll
        for (int r = 0; r < 4; ++r)
          if ((mb >> (sb + r)) & 1) sacc[nf][r] = NEGINF;
      }
    }
#pragma unroll
    for (int nf = 0; nf < 4; ++nf)
#pragma unroll
      for (int r = 0; r < 4; ++r) rmax = fmaxf(rmax, sacc[nf][r]);
    rmax = fmaxf(rmax, __shfl_xor(rmax, 16, 64));
    rmax = fmaxf(rmax, __shfl_xor(rmax, 32, 64));
    const float rm = rmax + cb;                  // row max in score space

    // defer-max: rescale only when some row grew past m_p + 8
    if (!__all(rm <= m_p + 8.0f)) {
      float m_new = fmaxf(m_p, rm);
      float scl = __expf(m_p - m_new);
      m_p = m_new;
      l_p *= scl;
#pragma unroll
      for (int r = 0; r < 4; ++r) {
        float so = __shfl(scl, g * 4 + r, 64);
#pragma unroll
        for (int nf2 = 0; nf2 < 4; ++nf2) o[nf2][r] *= so;
      }
    }
    const float msh = m_p - cb;
    float rsum = 0.f;
    bf16x8 pa[2];
#pragma unroll
    for (int kk = 0; kk < 2; ++kk)
#pragma unroll
      for (int j = 0; j < 8; ++j) {
        float e = __expf(sacc[2 * kk + (j >> 2)][j & 3] - msh);
        rsum += e;
        pa[kk][j] = (bf16)e;
      }
    rsum += __shfl_xor(rsum, 16, 64);
    rsum += __shfl_xor(rsum, 32, 64);
    l_p += rsum;

    // PV
    __builtin_amdgcn_s_setprio(1);
#pragma unroll
    for (int kk = 0; kk < 2; ++kk) {
#pragma unroll
      for (int nf2 = 0; nf2 < 4; ++nf2) {
        bf16x8 vbf = *(const bf16x8*)(Vs + swz((nf2 * 16 + c) * 128 + kk * 64 + g * 16));
        o[nf2] = __builtin_amdgcn_mfma_f32_16x16x32_bf16(pa[kk], vbf, o[nf2], 0, 0, 0);
      }
    }
    __builtin_amdgcn_s_setprio(0);

    if (it < SEQ / 64 - 1) {
      asm volatile("s_waitcnt vmcnt(0)" ::: "memory");  // tile it+1 landed
      __syncthreads();                                  // buf reuse safety
    }
  }
  // epilogue: O rows t = t0 + w*16 + g*4 + r; l lives at lane c'=g*4+r
#pragma unroll
  for (int r = 0; r < 4; ++r) {
    float lo = __shfl(l_p, g * 4 + r, 64);
    float inv = 1.0f / lo;
    int t = t0 + w * 16 + g * 4 + r;
#pragma unroll
    for (int nf2 = 0; nf2 < 4; ++nf2) {
      int dd = nf2 * 16 + c;
      attn_out[((size_t)t * NBATCH + b) * EMB + h * HD + dd] = (bf16)(o[nf2][r] * inv);
    }
  }
#undef ISSUE
}

extern "C" void kernel_launch(void* const* d_in, const int* in_sizes, int n_in,
                              void* d_out, int out_size, void* d_ws, size_t ws_size,
                              hipStream_t stream) {
  const float* query = (const float*)d_in[0];
  const float* key_ = (const float*)d_in[1];
  const float* value = (const float*)d_in[2];
  const unsigned char* kpm = (const unsigned char*)d_in[3];
  const float* Wq = (const float*)d_in[4];
  const float* bq = (const float*)d_in[5];
  const float* Wk = (const float*)d_in[6];
  const float* bk = (const float*)d_in[7];
  const float* Wv = (const float*)d_in[8];
  const float* bv = (const float*)d_in[9];
  const float* Wo = (const float*)d_in[10];
  const float* bo = (const float*)d_in[11];
  const float* rel_bias = (const float*)d_in[12];
  float* out = (float*)d_out;

  char* ws = (char*)d_ws;
  const size_t SZb = (size_t)SEQ * NBATCH * EMB * sizeof(bf16);  // 6.29 MB
  const size_t WSZ = (size_t)EMB * EMB * sizeof(bf16);           // 1.18 MB
  bf16* qbb = (bf16*)(ws);
  bf16* vbb = (bf16*)(ws + SZb);
  bf16* gk  = (bf16*)(ws + 2 * SZb);      // K tile images
  bf16* gv  = (bf16*)(ws + 3 * SZb);      // V tile images
  bf16* attnb = vbb;                      // vb dead after k_repack_v
  bf16* Wt3 = (bf16*)(ws + 4 * SZb);
  bf16* Wto = (bf16*)(ws + 4 * SZb + 3 * WSZ);
  float* bias_tab = (float*)(ws + 4 * SZb + 4 * WSZ);
  unsigned long long* mbits =
      (unsigned long long*)(ws + 4 * SZb + 4 * WSZ + (size_t)NH * NREL * sizeof(float) + 64);

  k_bias_table<<<16, 256, 0, stream>>>(rel_bias, bias_tab);
  k_maskbits<<<1, 64, 0, stream>>>(kpm, mbits);
  k_cvt_w<<<dim3(12, 12, 4), 256, 0, stream>>>(Wq, Wk, Wv, Wo, Wt3, Wto);
  k_proj_qkv<<<dim3(32, 6, 3), 256, 0, stream>>>(
      query, key_, value, Wt3, bq, bk, bv, qbb, gk, vbb);
  k_repack_v<<<dim3(NBATCH * NH, SEQ / 64), 256, 0, stream>>>(vbb, gv);
  k_attn<<<dim3(NBATCH * NH, SEQ / 64), 256, 0, stream>>>(qbb, gk, gv, mbits, bias_tab, attnb);
  k_proj_out<<<dim3(32, 6), 256, 0, stream>>>(attnb, Wto, bo, out);
}

// Round 6
// 141.520 us; speedup vs baseline: 1.4069x; 1.0489x over previous
//
#include <hip/hip_runtime.h>
#include <hip/hip_bf16.h>

typedef __bf16 bf16;
typedef __bf16 bf16x8 __attribute__((ext_vector_type(8)));
typedef float f32x4 __attribute__((ext_vector_type(4)));

#define EMB 768
#define NH 12
#define HD 64
#define SEQ 2048
#define NBATCH 2
#define NREL (2 * SEQ - 1)

// XOR-swizzle for 128B-row-stride LDS tiles (bits 9:7 -> 6:4). Involution.
__device__ __forceinline__ int swz(int bo) { return bo ^ ((bo >> 3) & 0x70); }
// K-row permutation making PV A-fragments lane-local (verified r2-r5).
__device__ __forceinline__ int kpos(int s) {
  return (s & 0x23) | ((s & 0x04) << 2) | ((s & 0x18) >> 1);
}

// global -> LDS async 16B copy (wave-uniform LDS base, lane i at +i*16).
typedef __attribute__((address_space(3))) unsigned int lds_u32;
typedef __attribute__((address_space(1))) unsigned int glb_u32;
__device__ __forceinline__ void gld16(const void* g, void* l) {
  __builtin_amdgcn_global_load_lds((const glb_u32*)g, (lds_u32*)l, 16, 0, 0);
}

// ---------------- bias bucket table: bias_tab[h][rel + 2047] ----------------
__global__ void k_bias_table(const float* __restrict__ rel_bias,
                             float* __restrict__ bias_tab) {
  int i = blockIdx.x * 256 + threadIdx.x;
  if (i >= NREL) return;
  int rel = i - (SEQ - 1);            // rel = s - t
  int bkt = (rel > 0) ? 16 : 0;
  int rp = rel < 0 ? -rel : rel;
  if (rp < 8) {
    bkt += rp;
  } else {
    float lf = (logf((float)rp * 0.125f) / 2.7725887222397811f) * 8.0f;
    int large = 8 + (int)lf;
    bkt += (large < 15) ? large : 15;
  }
  for (int h = 0; h < NH; ++h)
    bias_tab[h * NREL + i] = rel_bias[bkt * NH + h];
}

// -------- mask bits: one wave per word; mbits[b*32+w] bit s = mask[b][w*64+s]
__global__ void k_maskbits(const unsigned char* __restrict__ mask,
                           unsigned long long* __restrict__ mbits) {
  int wid = blockIdx.x * 4 + (threadIdx.x >> 6);   // 0..63
  int lane = threadIdx.x & 63;
  int b = wid >> 5, wd = wid & 31;
  unsigned long long m = __ballot(mask[b * SEQ + wd * 64 + lane] != 0);
  if (lane == 0) mbits[wid] = m;
}

// ------- W convert+transpose (LDS-tiled, coalesced): W[k][n] f32 -> Wt[n][k]
__global__ __launch_bounds__(256) void k_cvt_w(
    const float* __restrict__ Wq, const float* __restrict__ Wk,
    const float* __restrict__ Wv, const float* __restrict__ Wo,
    bf16* __restrict__ Wt3, bf16* __restrict__ Wto) {
  __shared__ __align__(16) bf16 T[64 * 64];   // [k][n] swizzled
  const int z = blockIdx.z;
  const float* W = z == 0 ? Wq : z == 1 ? Wk : z == 2 ? Wv : Wo;
  bf16* O = z < 3 ? Wt3 + (size_t)z * EMB * EMB : Wto;
  const int k0 = blockIdx.x * 64, n0 = blockIdx.y * 64;
  const int tid = threadIdx.x;
  // read: row = tid>>2 (64 rows), 16 consecutive floats at col (tid&3)*16
  {
    int row = tid >> 2, colb = (tid & 3) * 16;
    const float* wp = W + (size_t)(k0 + row) * EMB + n0 + colb;
#pragma unroll
    for (int q = 0; q < 16; q += 4) {
      float4 f = *(const float4*)(wp + q);
      union { bf16 e[4]; unsigned long long u; } pk;
      pk.e[0] = (bf16)f.x; pk.e[1] = (bf16)f.y;
      pk.e[2] = (bf16)f.z; pk.e[3] = (bf16)f.w;
      *(unsigned long long*)((char*)T + swz(row * 128 + (colb + q) * 2)) = pk.u;
    }
  }
  __syncthreads();
  // write: output row n = tid>>2, 16 k at (tid&3)*16, two uint4 stores
  {
    int n = tid >> 2, kb = (tid & 3) * 16;
    union { bf16 e[16]; uint4 u[2]; } pk;
#pragma unroll
    for (int q = 0; q < 16; ++q)
      pk.e[q] = *(const bf16*)((char*)T + swz((kb + q) * 128 + n * 2));
    *(uint4*)(O + (size_t)(n0 + n) * EMB + k0 + kb) = pk.u[0];
    *(uint4*)(O + (size_t)(n0 + n) * EMB + k0 + kb + 8) = pk.u[1];
  }
}

// ---- QKV projection GEMM: 128x128 tile, BK=64 (m97 structure) --------------
// z=0: Q scaled -> row-major.  z=1: K -> pre-swizzled tile image gk.
// z=2: V -> row-major (repacked by k_repack_v).
__global__ __launch_bounds__(256) void k_proj_qkv(
    const float* __restrict__ Xq, const float* __restrict__ Xk,
    const float* __restrict__ Xv, const bf16* __restrict__ Wt3,
    const float* __restrict__ bq, const float* __restrict__ bk,
    const float* __restrict__ bv, bf16* __restrict__ oq,
    bf16* __restrict__ gk, bf16* __restrict__ ov) {
  __shared__ __align__(16) bf16 As[128 * 64];   // [m][k] linear
  __shared__ __align__(16) bf16 Bs[128 * 64];   // [n][k] linear
  const int z = blockIdx.z;
  const float* X = z == 0 ? Xq : z == 1 ? Xk : Xv;
  const bf16* Wt = Wt3 + (size_t)z * EMB * EMB;
  const float* bias = z == 0 ? bq : z == 1 ? bk : bv;
  bf16* C = z == 0 ? oq : ov;
  const float scale = z == 0 ? 0.125f : 1.0f;

  const int m0 = blockIdx.x * 128, n0 = blockIdx.y * 128;
  const int tid = threadIdx.x, lane = tid & 63, w = tid >> 6;
  const int c = lane & 15, g = lane >> 4;
  const int mo = (w >> 1) * 64, no = (w & 1) * 64;

  f32x4 acc[4][4] = {};
  for (int k0 = 0; k0 < EMB; k0 += 64) {
    __syncthreads();
#pragma unroll
    for (int jj = 0; jj < 4; ++jj) {
      gld16(Wt + (size_t)(n0 + w * 32 + jj * 8 + (lane >> 3)) * EMB + k0 + (lane & 7) * 8,
            (char*)Bs + (w * 32 + jj * 8) * 128);
    }
#pragma unroll
    for (int j = 0; j < 4; ++j) {
      int row = (tid >> 3) + j * 32;
      const float* ap = X + (size_t)(m0 + row) * EMB + k0 + (tid & 7) * 8;
      float4 f0 = *(const float4*)ap, f1 = *(const float4*)(ap + 4);
      bf16x8 hh;
      hh[0] = (bf16)f0.x; hh[1] = (bf16)f0.y; hh[2] = (bf16)f0.z; hh[3] = (bf16)f0.w;
      hh[4] = (bf16)f1.x; hh[5] = (bf16)f1.y; hh[6] = (bf16)f1.z; hh[7] = (bf16)f1.w;
      *(bf16x8*)((char*)As + tid * 16 + j * 4096) = hh;
    }
    __syncthreads();
#pragma unroll
    for (int kk = 0; kk < 2; ++kk) {
      bf16x8 av[4], bvf[4];
#pragma unroll
      for (int mf = 0; mf < 4; ++mf)
        av[mf] = *(const bf16x8*)((char*)As + (mo + mf * 16 + c) * 128 + kk * 64 + g * 16);
#pragma unroll
      for (int nf = 0; nf < 4; ++nf)
        bvf[nf] = *(const bf16x8*)((char*)Bs + (no + nf * 16 + c) * 128 + kk * 64 + g * 16);
#pragma unroll
      for (int mf = 0; mf < 4; ++mf)
#pragma unroll
        for (int nf = 0; nf < 4; ++nf)
          acc[mf][nf] = __builtin_amdgcn_mfma_f32_16x16x32_bf16(bvf[nf], av[mf], acc[mf][nf], 0, 0, 0);
    }
  }
#pragma unroll
  for (int nf = 0; nf < 4; ++nf) {
    int n = n0 + no + nf * 16 + g * 4;
    float4 b4 = *(const float4*)&bias[n];
#pragma unroll
    for (int mf = 0; mf < 4; ++mf) {
      int m = m0 + mo + mf * 16 + c;
      union { bf16 e[4]; uint2 u; } pk;
      pk.e[0] = (bf16)((acc[mf][nf][0] + b4.x) * scale);
      pk.e[1] = (bf16)((acc[mf][nf][1] + b4.y) * scale);
      pk.e[2] = (bf16)((acc[mf][nf][2] + b4.z) * scale);
      pk.e[3] = (bf16)((acc[mf][nf][3] + b4.w) * scale);
      if (z == 1) {          // K tile image: byte swz(kpos(s)*128 + slot) = K[s]
        int t = m >> 1, bb = m & 1;
        int hh = n >> 6, d = n & 63;
        char* base = (char*)gk + ((size_t)(bb * NH + hh) * 32 + (t >> 6)) * 8192;
        *(uint2*)(base + swz(kpos(t & 63) * 128 + (d & ~7) * 2) + (d & 4) * 2) = pk.u;
      } else {
        *(uint2*)(C + (size_t)m * EMB + n) = pk.u;
      }
    }
  }
}

// ---- output projection: bf16 A[4096][768] @ Wto[n][k] + bo -> f32 ----------
__global__ __launch_bounds__(256) void k_proj_out(
    const bf16* __restrict__ A, const bf16* __restrict__ Wt,
    const float* __restrict__ bias, float* __restrict__ out) {
  __shared__ __align__(16) bf16 As[128 * 64];
  __shared__ __align__(16) bf16 Bs[128 * 64];
  const int m0 = blockIdx.x * 128, n0 = blockIdx.y * 128;
  const int tid = threadIdx.x, lane = tid & 63, w = tid >> 6;
  const int c = lane & 15, g = lane >> 4;
  const int mo = (w >> 1) * 64, no = (w & 1) * 64;
  f32x4 acc[4][4] = {};
  for (int k0 = 0; k0 < EMB; k0 += 64) {
    __syncthreads();
#pragma unroll
    for (int jj = 0; jj < 4; ++jj) {
      int r = w * 32 + jj * 8 + (lane >> 3);
      gld16(A + (size_t)(m0 + r) * EMB + k0 + (lane & 7) * 8,
            (char*)As + (w * 32 + jj * 8) * 128);
      gld16(Wt + (size_t)(n0 + r) * EMB + k0 + (lane & 7) * 8,
            (char*)Bs + (w * 32 + jj * 8) * 128);
    }
    __syncthreads();
#pragma unroll
    for (int kk = 0; kk < 2; ++kk) {
      bf16x8 av[4], bvf[4];
#pragma unroll
      for (int mf = 0; mf < 4; ++mf)
        av[mf] = *(const bf16x8*)((char*)As + (mo + mf * 16 + c) * 128 + kk * 64 + g * 16);
#pragma unroll
      for (int nf = 0; nf < 4; ++nf)
        bvf[nf] = *(const bf16x8*)((char*)Bs + (no + nf * 16 + c) * 128 + kk * 64 + g * 16);
#pragma unroll
      for (int mf = 0; mf < 4; ++mf)
#pragma unroll
        for (int nf = 0; nf < 4; ++nf)
          acc[mf][nf] = __builtin_amdgcn_mfma_f32_16x16x32_bf16(bvf[nf], av[mf], acc[mf][nf], 0, 0, 0);
    }
  }
#pragma unroll
  for (int nf = 0; nf < 4; ++nf) {
    int n = n0 + no + nf * 16 + g * 4;
    float4 b4 = *(const float4*)&bias[n];
#pragma unroll
    for (int mf = 0; mf < 4; ++mf) {
      int m = m0 + mo + mf * 16 + c;
      float4 v;
      v.x = acc[mf][nf][0] + b4.x;
      v.y = acc[mf][nf][1] + b4.y;
      v.z = acc[mf][nf][2] + b4.z;
      v.w = acc[mf][nf][3] + b4.w;
      *(float4*)(out + (size_t)m * EMB + n) = v;
    }
  }
}

// ---- V repack: vb row-major [4096][768] -> gv tile images ------------------
// image byte swz(d*128 + c16*16) = V^T[d][s0 + c16*8 .. +8]
__global__ __launch_bounds__(256) void k_repack_v(const bf16* __restrict__ vb,
                                                  bf16* __restrict__ gv) {
  __shared__ __align__(16) bf16 T[64 * 64];  // [s][d] swizzled
  const int bh = blockIdx.x;
  const int b = bh / NH, h = bh % NH;
  const int s0 = blockIdx.y * 64;
  const int tid = threadIdx.x;
#pragma unroll
  for (int ii = 0; ii < 2; ++ii) {
    int i = tid * 2 + ii;
    int s = i >> 3, c16 = i & 7;
    uint4 v = *(const uint4*)(vb + (size_t)((s0 + s) * NBATCH + b) * EMB + h * 64 + c16 * 8);
    *(uint4*)((char*)T + swz(s * 128 + c16 * 16)) = v;
  }
  __syncthreads();
  char* out = (char*)gv + ((size_t)bh * 32 + blockIdx.y) * 8192;
#pragma unroll
  for (int jj = 0; jj < 2; ++jj) {
    int j = tid * 2 + jj;
    int d = j >> 3, c16 = j & 7;
    union { bf16 e[8]; uint4 u; } pk;
#pragma unroll
    for (int q = 0; q < 8; ++q)
      pk.e[q] = *(const bf16*)((char*)T + swz((c16 * 8 + q) * 128 + d * 2));
    *(uint4*)(out + swz(d * 128 + c16 * 16)) = pk.u;
  }
}

// ----------------------------- flash attention ------------------------------
// Pre-packed K/V tile images + gld16 double-buffer, compact bias slab (Bslow,
// covers |rel|<192; const-bias elsewhere), maskbits, defer-max, setprio.
__global__ __launch_bounds__(256, 4) void k_attn(
    const bf16* __restrict__ qb, const bf16* __restrict__ gk,
    const bf16* __restrict__ gv, const unsigned long long* __restrict__ mbits,
    const float* __restrict__ bias_tab, bf16* __restrict__ attn_out) {
  __shared__ __align__(16) bf16 KV[2][2][4096];  // [buf][K/V][8KB image]
  __shared__ float Bslow[384];                   // bias for rel in [-192,192)
  const int bh = blockIdx.x;
  const int b = bh / NH, h = bh % NH;
  const int t0 = blockIdx.y * 64;
  const int tid = threadIdx.x;
  const int lane = tid & 63, w = tid >> 6;
  const int c = lane & 15, g = lane >> 4;
  const float NEGINF = -__builtin_inff();
  const int tl = w * 16 + c;                   // this lane's t (block-local)

  const char* kimg = (const char*)gk + (size_t)bh * 32 * 8192;
  const char* vimg = (const char*)gv + (size_t)bh * 32 * 8192;

#define ISSUE(IT, BUF) do {                                                  \
    const char* ks_ = kimg + (size_t)(IT) * 8192;                            \
    const char* vs_ = vimg + (size_t)(IT) * 8192;                            \
    _Pragma("unroll") for (int jj = 0; jj < 2; ++jj) {                       \
      int ch = w * 2 + jj;                                                   \
      gld16(ks_ + ch * 1024 + lane * 16, (char*)KV[BUF][0] + ch * 1024);     \
      gld16(vs_ + ch * 1024 + lane * 16, (char*)KV[BUF][1] + ch * 1024);     \
    }                                                                        \
  } while (0)

  ISSUE(0, 0);
  // Q fragments (B operand), loop-invariant
  bf16x8 qf[2];
  {
    const bf16* qp = qb + (size_t)((t0 + tl) * NBATCH + b) * EMB + h * 64 + g * 8;
    qf[0] = *(const bf16x8*)qp;
    qf[1] = *(const bf16x8*)(qp + 32);
  }
  // bias slab: Bslow[j] = btab[j - 192]; lookup idx = rel + 192
  const float* btab = bias_tab + h * NREL + (SEQ - 1);
  for (int j = tid; j < 384; j += 256) Bslow[j] = btab[j - 192];
  const float cpos = btab[SEQ - 1];            // bucket 31 (rel >= 128)
  const float cneg = btab[-(SEQ - 1)];         // bucket 15 (rel <= -128)

  float m_p = -1e30f, l_p = 0.f;
  f32x4 o[4] = {};

  asm volatile("s_waitcnt vmcnt(0)" ::: "memory");
  __syncthreads();

  for (int it = 0; it < SEQ / 64; ++it) {
    const int cur = it & 1;
    if (it < SEQ / 64 - 1) ISSUE(it + 1, cur ^ 1);
    const unsigned long long mb = mbits[b * 32 + it];
    const char* Ks = (const char*)KV[cur][0];
    const char* Vs = (const char*)KV[cur][1];

    // QK^T (swapped): sacc[nf][r] = S_raw[t0+tl][s0 + 32*(nf>>1)+g*8+(nf&1)*4+r]
    f32x4 sacc[4] = {};
    __builtin_amdgcn_s_setprio(1);
#pragma unroll
    for (int kk = 0; kk < 2; ++kk) {
#pragma unroll
      for (int nf = 0; nf < 4; ++nf) {
        bf16x8 kf = *(const bf16x8*)(Ks + swz((nf * 16 + c) * 128 + kk * 64 + g * 16));
        sacc[nf] = __builtin_amdgcn_mfma_f32_16x16x32_bf16(kf, qf[kk], sacc[nf], 0, 0, 0);
      }
    }
    __builtin_amdgcn_s_setprio(0);

    const int s0 = it * 64;
    const int d = s0 - t0;
    const bool slow = (d > -192) && (d < 192);
    const float cb = slow ? 0.f : (d >= 192 ? cpos : cneg);

    float rmax = NEGINF;
    if (slow) {
      const int bidx = d - tl + 192;
#pragma unroll
      for (int nf = 0; nf < 4; ++nf) {
        int sb = 32 * (nf >> 1) + g * 8 + (nf & 1) * 4;
#pragma unroll
        for (int r = 0; r < 4; ++r) sacc[nf][r] += Bslow[bidx + sb + r];
      }
    }
    if (mb) {
#pragma unroll
      for (int nf = 0; nf < 4; ++nf) {
        int sb = 32 * (nf >> 1) + g * 8 + (nf & 1) * 4;
#pragma unroll
        for (int r = 0; r < 4; ++r)
          if ((mb >> (sb + r)) & 1) sacc[nf][r] = NEGINF;
      }
    }
#pragma unroll
    for (int nf = 0; nf < 4; ++nf)
#pragma unroll
      for (int r = 0; r < 4; ++r) rmax = fmaxf(rmax, sacc[nf][r]);
    rmax = fmaxf(rmax, __shfl_xor(rmax, 16, 64));
    rmax = fmaxf(rmax, __shfl_xor(rmax, 32, 64));
    const float rm = rmax + cb;                  // row max in score space

    // defer-max: rescale only when some row grew past m_p + 8
    if (!__all(rm <= m_p + 8.0f)) {
      float m_new = fmaxf(m_p, rm);
      float scl = __expf(m_p - m_new);
      m_p = m_new;
      l_p *= scl;
#pragma unroll
      for (int r = 0; r < 4; ++r) {
        float so = __shfl(scl, g * 4 + r, 64);
#pragma unroll
        for (int nf2 = 0; nf2 < 4; ++nf2) o[nf2][r] *= so;
      }
    }
    const float msh = m_p - cb;
    float rsum = 0.f;
    bf16x8 pa[2];
#pragma unroll
    for (int kk = 0; kk < 2; ++kk)
#pragma unroll
      for (int j = 0; j < 8; ++j) {
        float e = __expf(sacc[2 * kk + (j >> 2)][j & 3] - msh);
        rsum += e;
        pa[kk][j] = (bf16)e;
      }
    rsum += __shfl_xor(rsum, 16, 64);
    rsum += __shfl_xor(rsum, 32, 64);
    l_p += rsum;

    // PV
    __builtin_amdgcn_s_setprio(1);
#pragma unroll
    for (int kk = 0; kk < 2; ++kk) {
#pragma unroll
      for (int nf2 = 0; nf2 < 4; ++nf2) {
        bf16x8 vbf = *(const bf16x8*)(Vs + swz((nf2 * 16 + c) * 128 + kk * 64 + g * 16));
        o[nf2] = __builtin_amdgcn_mfma_f32_16x16x32_bf16(pa[kk], vbf, o[nf2], 0, 0, 0);
      }
    }
    __builtin_amdgcn_s_setprio(0);

    if (it < SEQ / 64 - 1) {
      asm volatile("s_waitcnt vmcnt(0)" ::: "memory");  // tile it+1 landed
      __syncthreads();                                  // buf reuse safety
    }
  }
  // epilogue: O rows t = t0 + w*16 + g*4 + r; l lives at lane c'=g*4+r
#pragma unroll
  for (int r = 0; r < 4; ++r) {
    float lo = __shfl(l_p, g * 4 + r, 64);
    float inv = 1.0f / lo;
    int t = t0 + w * 16 + g * 4 + r;
#pragma unroll
    for (int nf2 = 0; nf2 < 4; ++nf2) {
      int dd = nf2 * 16 + c;
      attn_out[((size_t)t * NBATCH + b) * EMB + h * HD + dd] = (bf16)(o[nf2][r] * inv);
    }
  }
#undef ISSUE
}

extern "C" void kernel_launch(void* const* d_in, const int* in_sizes, int n_in,
                              void* d_out, int out_size, void* d_ws, size_t ws_size,
                              hipStream_t stream) {
  const float* query = (const float*)d_in[0];
  const float* key_ = (const float*)d_in[1];
  const float* value = (const float*)d_in[2];
  const unsigned char* kpm = (const unsigned char*)d_in[3];
  const float* Wq = (const float*)d_in[4];
  const float* bq = (const float*)d_in[5];
  const float* Wk = (const float*)d_in[6];
  const float* bk = (const float*)d_in[7];
  const float* Wv = (const float*)d_in[8];
  const float* bv = (const float*)d_in[9];
  const float* Wo = (const float*)d_in[10];
  const float* bo = (const float*)d_in[11];
  const float* rel_bias = (const float*)d_in[12];
  float* out = (float*)d_out;

  char* ws = (char*)d_ws;
  const size_t SZb = (size_t)SEQ * NBATCH * EMB * sizeof(bf16);  // 6.29 MB
  const size_t WSZ = (size_t)EMB * EMB * sizeof(bf16);           // 1.18 MB
  bf16* qbb = (bf16*)(ws);
  bf16* vbb = (bf16*)(ws + SZb);
  bf16* gk  = (bf16*)(ws + 2 * SZb);      // K tile images
  bf16* gv  = (bf16*)(ws + 3 * SZb);      // V tile images
  bf16* attnb = vbb;                      // vb dead after k_repack_v
  bf16* Wt3 = (bf16*)(ws + 4 * SZb);
  bf16* Wto = (bf16*)(ws + 4 * SZb + 3 * WSZ);
  float* bias_tab = (float*)(ws + 4 * SZb + 4 * WSZ);
  unsigned long long* mbits =
      (unsigned long long*)(ws + 4 * SZb + 4 * WSZ + (size_t)NH * NREL * sizeof(float) + 64);

  k_bias_table<<<16, 256, 0, stream>>>(rel_bias, bias_tab);
  k_maskbits<<<16, 256, 0, stream>>>(kpm, mbits);
  k_cvt_w<<<dim3(12, 12, 4), 256, 0, stream>>>(Wq, Wk, Wv, Wo, Wt3, Wto);
  k_proj_qkv<<<dim3(32, 6, 3), 256, 0, stream>>>(
      query, key_, value, Wt3, bq, bk, bv, qbb, gk, vbb);
  k_repack_v<<<dim3(NBATCH * NH, SEQ / 64), 256, 0, stream>>>(vbb, gv);
  k_attn<<<dim3(NBATCH * NH, SEQ / 64), 256, 0, stream>>>(qbb, gk, gv, mbits, bias_tab, attnb);
  k_proj_out<<<dim3(32, 6), 256, 0, stream>>>(attnb, Wto, bo, out);
}

// Round 7
// 110.237 us; speedup vs baseline: 1.8062x; 1.2838x over previous
//
#include <hip/hip_runtime.h>
#include <hip/hip_bf16.h>

typedef __bf16 bf16;
typedef __bf16 bf16x8 __attribute__((ext_vector_type(8)));
typedef float f32x4 __attribute__((ext_vector_type(4)));

#define EMB 768
#define NH 12
#define HD 64
#define SEQ 2048
#define NBATCH 2
#define NREL (2 * SEQ - 1)

// XOR-swizzle for 128B-row-stride LDS tiles (bits 9:7 -> 6:4). Involution.
__device__ __forceinline__ int swz(int bo) { return bo ^ ((bo >> 3) & 0x70); }
// XOR-swizzle for 256B-row-stride LDS tiles (bits 10:8 -> 6:4). Involution.
__device__ __forceinline__ int swz256(int bo) { return bo ^ ((bo >> 4) & 0x70); }
// K-row permutation making PV A-fragments lane-local (verified r2-r6).
__device__ __forceinline__ int kpos(int s) {
  return (s & 0x23) | ((s & 0x04) << 2) | ((s & 0x18) >> 1);
}

// global -> LDS async 16B copy (wave-uniform LDS base, lane i at +i*16).
typedef __attribute__((address_space(3))) unsigned int lds_u32;
typedef __attribute__((address_space(1))) unsigned int glb_u32;
__device__ __forceinline__ void gld16(const void* g, void* l) {
  __builtin_amdgcn_global_load_lds((const glb_u32*)g, (lds_u32*)l, 16, 0, 0);
}

// ---------------- bias bucket table: bias_tab[h][rel + 2047] ----------------
__global__ void k_bias_table(const float* __restrict__ rel_bias,
                             float* __restrict__ bias_tab) {
  int i = blockIdx.x * 256 + threadIdx.x;
  if (i >= NREL) return;
  int rel = i - (SEQ - 1);            // rel = s - t
  int bkt = (rel > 0) ? 16 : 0;
  int rp = rel < 0 ? -rel : rel;
  if (rp < 8) {
    bkt += rp;
  } else {
    float lf = (logf((float)rp * 0.125f) / 2.7725887222397811f) * 8.0f;
    int large = 8 + (int)lf;
    bkt += (large < 15) ? large : 15;
  }
  for (int h = 0; h < NH; ++h)
    bias_tab[h * NREL + i] = rel_bias[bkt * NH + h];
}

// -------- mask bits: one wave per word; mbits[b*32+w] bit s = mask[b][w*64+s]
__global__ void k_maskbits(const unsigned char* __restrict__ mask,
                           unsigned long long* __restrict__ mbits) {
  int wid = blockIdx.x * 4 + (threadIdx.x >> 6);   // 0..63
  int lane = threadIdx.x & 63;
  int b = wid >> 5, wd = wid & 31;
  unsigned long long m = __ballot(mask[b * SEQ + wd * 64 + lane] != 0);
  if (lane == 0) mbits[wid] = m;
}

// ------- X convert: f32 X -> bf16 128x64 swizzled tile images ---------------
// ximg[((z*32+mb)*12+ks)] tile: byte swz(mr*128 + kc*2) = X[m0+mr][k0+kc]
__global__ __launch_bounds__(256) void k_cvt_x(
    const float* __restrict__ Xq, const float* __restrict__ Xk,
    const float* __restrict__ Xv, bf16* __restrict__ ximg) {
  const int z = blockIdx.z;
  const float* X = z == 0 ? Xq : z == 1 ? Xk : Xv;
  const int m0 = blockIdx.x * 128, k0 = blockIdx.y * 64;
  char* img = (char*)ximg + ((size_t)(z * 32 + blockIdx.x) * 12 + blockIdx.y) * 16384;
#pragma unroll
  for (int it = 0; it < 4; ++it) {
    int i = threadIdx.x + it * 256;
    int mr = i >> 3, kc8 = (i & 7) * 8;
    const float* xp = X + (size_t)(m0 + mr) * EMB + k0 + kc8;
    float4 f0 = *(const float4*)xp, f1 = *(const float4*)(xp + 4);
    bf16x8 hh;
    hh[0] = (bf16)f0.x; hh[1] = (bf16)f0.y; hh[2] = (bf16)f0.z; hh[3] = (bf16)f0.w;
    hh[4] = (bf16)f1.x; hh[5] = (bf16)f1.y; hh[6] = (bf16)f1.z; hh[7] = (bf16)f1.w;
    *(bf16x8*)(img + swz(mr * 128 + kc8 * 2)) = hh;
  }
}

// ------- W convert+transpose: W[k][n] f32 -> 128x64 swizzled tile images ----
// wimg[((z*6+nb)*12+ks)] tile: byte swz(nr*128 + kc*2) = W[k0+kc][n0+nr]
__global__ __launch_bounds__(256) void k_cvt_w(
    const float* __restrict__ Wq, const float* __restrict__ Wk,
    const float* __restrict__ Wv, const float* __restrict__ Wo,
    bf16* __restrict__ wimg) {
  __shared__ __align__(16) bf16 T[64 * 128];   // [k][n], 256B rows, swz256
  const int z = blockIdx.z;
  const float* W = z == 0 ? Wq : z == 1 ? Wk : z == 2 ? Wv : Wo;
  const int nb = blockIdx.x, ks = blockIdx.y;
  const int n0 = nb * 128, k0 = ks * 64;
  const int tid = threadIdx.x;
  {
    int kk = tid >> 2, nn0 = (tid & 3) * 32;
    const float* wp = W + (size_t)(k0 + kk) * EMB + n0 + nn0;
#pragma unroll
    for (int jq = 0; jq < 4; ++jq) {
      float4 f0 = *(const float4*)(wp + jq * 8);
      float4 f1 = *(const float4*)(wp + jq * 8 + 4);
      bf16x8 hh;
      hh[0] = (bf16)f0.x; hh[1] = (bf16)f0.y; hh[2] = (bf16)f0.z; hh[3] = (bf16)f0.w;
      hh[4] = (bf16)f1.x; hh[5] = (bf16)f1.y; hh[6] = (bf16)f1.z; hh[7] = (bf16)f1.w;
      *(bf16x8*)((char*)T + swz256(kk * 256 + (nn0 + jq * 8) * 2)) = hh;
    }
  }
  __syncthreads();
  {
    int nr = tid >> 1, kh = tid & 1;
    char* img = (char*)wimg + ((size_t)(z * 6 + nb) * 12 + ks) * 16384;
#pragma unroll
    for (int jq = 0; jq < 4; ++jq) {
      union { bf16 e[8]; uint4 u; } pk;
#pragma unroll
      for (int q = 0; q < 8; ++q)
        pk.e[q] = *(const bf16*)((char*)T + swz256((kh * 32 + jq * 8 + q) * 256 + nr * 2));
      *(uint4*)(img + swz(nr * 128 + (kh * 32 + jq * 8) * 2)) = pk.u;
    }
  }
}

// ---- QKV projection GEMM: pure-gld16 dbuf pipeline over tile images --------
// z=0: Q scaled -> row-major. z=1: K -> attn K-tile images gk.
// z=2: V -> attn V-tile images gv (direct, transposed).
__global__ __launch_bounds__(256) void k_proj_qkv(
    const bf16* __restrict__ ximg, const bf16* __restrict__ wimg,
    const float* __restrict__ bq, const float* __restrict__ bk,
    const float* __restrict__ bv, bf16* __restrict__ oq,
    bf16* __restrict__ gk, bf16* __restrict__ gv) {
  __shared__ __align__(16) bf16 AB[2][2][8192];  // [buf][A/B][16KB tile]
  const int z = blockIdx.z;
  const float* bias = z == 0 ? bq : z == 1 ? bk : bv;
  const float scale = z == 0 ? 0.125f : 1.0f;
  const int mb = blockIdx.x, nb = blockIdx.y;
  const int m0 = mb * 128, n0 = nb * 128;
  const int tid = threadIdx.x, lane = tid & 63, w = tid >> 6;
  const int c = lane & 15, g = lane >> 4;
  const int mo = (w >> 1) * 64, no = (w & 1) * 64;
  const char* abase = (const char*)ximg + (size_t)(z * 32 + mb) * 12 * 16384;
  const char* bbase = (const char*)wimg + (size_t)(z * 6 + nb) * 12 * 16384;

#define PISSUE(KS, BUF) do {                                               \
    const char* a_ = abase + (size_t)(KS) * 16384;                         \
    const char* b_ = bbase + (size_t)(KS) * 16384;                         \
    _Pragma("unroll") for (int ch = 0; ch < 4; ++ch) {                     \
      int ck = w * 4 + ch;                                                 \
      gld16(a_ + ck * 1024 + lane * 16, (char*)AB[BUF][0] + ck * 1024);    \
      gld16(b_ + ck * 1024 + lane * 16, (char*)AB[BUF][1] + ck * 1024);    \
    }                                                                      \
  } while (0)

  PISSUE(0, 0);
  f32x4 acc[4][4] = {};
  asm volatile("s_waitcnt vmcnt(0)" ::: "memory");
  __syncthreads();
  for (int ks = 0; ks < 12; ++ks) {
    const int cur = ks & 1;
    if (ks < 11) PISSUE(ks + 1, cur ^ 1);
    const char* As = (const char*)AB[cur][0];
    const char* Bs = (const char*)AB[cur][1];
    __builtin_amdgcn_s_setprio(1);
#pragma unroll
    for (int kk = 0; kk < 2; ++kk) {
      bf16x8 av[4], bvf[4];
#pragma unroll
      for (int mf = 0; mf < 4; ++mf)
        av[mf] = *(const bf16x8*)(As + swz((mo + mf * 16 + c) * 128 + kk * 64 + g * 16));
#pragma unroll
      for (int nf = 0; nf < 4; ++nf)
        bvf[nf] = *(const bf16x8*)(Bs + swz((no + nf * 16 + c) * 128 + kk * 64 + g * 16));
#pragma unroll
      for (int mf = 0; mf < 4; ++mf)
#pragma unroll
        for (int nf = 0; nf < 4; ++nf)
          acc[mf][nf] = __builtin_amdgcn_mfma_f32_16x16x32_bf16(bvf[nf], av[mf], acc[mf][nf], 0, 0, 0);
    }
    __builtin_amdgcn_s_setprio(0);
    if (ks < 11) {
      asm volatile("s_waitcnt vmcnt(0)" ::: "memory");
      __syncthreads();
    }
  }
  // epilogue: acc[mf][nf][r] = C[mo+mf*16+c][no+nf*16+g*4+r]
#pragma unroll
  for (int nf = 0; nf < 4; ++nf) {
    int n = n0 + no + nf * 16 + g * 4;
    float4 b4 = *(const float4*)&bias[n];
#pragma unroll
    for (int mf = 0; mf < 4; ++mf) {
      int m = m0 + mo + mf * 16 + c;
      float v0 = (acc[mf][nf][0] + b4.x) * scale;
      float v1 = (acc[mf][nf][1] + b4.y) * scale;
      float v2 = (acc[mf][nf][2] + b4.z) * scale;
      float v3 = (acc[mf][nf][3] + b4.w) * scale;
      if (z == 0) {
        union { bf16 e[4]; uint2 u; } pk;
        pk.e[0] = (bf16)v0; pk.e[1] = (bf16)v1; pk.e[2] = (bf16)v2; pk.e[3] = (bf16)v3;
        *(uint2*)(oq + (size_t)m * EMB + n) = pk.u;
      } else if (z == 1) {   // K image: byte swz(kpos(s)*128 + d*2) = K[s][d]
        int t = m >> 1, bb = m & 1;
        int hh = n >> 6, d = n & 63;
        union { bf16 e[4]; uint2 u; } pk;
        pk.e[0] = (bf16)v0; pk.e[1] = (bf16)v1; pk.e[2] = (bf16)v2; pk.e[3] = (bf16)v3;
        char* base = (char*)gk + ((size_t)(bb * NH + hh) * 32 + (t >> 6)) * 8192;
        *(uint2*)(base + swz(kpos(t & 63) * 128 + (d & ~7) * 2) + (d & 4) * 2) = pk.u;
      } else {               // V image: byte swz(d*128 + sc*2) = V[s0+sc][d]
        int s = m >> 1, bb = m & 1;
        int hh = n >> 6, d0 = n & 63;
        char* base = (char*)gv + ((size_t)(bb * NH + hh) * 32 + (s >> 6)) * 8192;
        int sc2 = (s & 63) * 2;
        *(bf16*)(base + (((d0 + 0) * 128 + sc2) ^ (((d0 + 0) & 7) << 4))) = (bf16)v0;
        *(bf16*)(base + (((d0 + 1) * 128 + sc2) ^ (((d0 + 1) & 7) << 4))) = (bf16)v1;
        *(bf16*)(base + (((d0 + 2) * 128 + sc2) ^ (((d0 + 2) & 7) << 4))) = (bf16)v2;
        *(bf16*)(base + (((d0 + 3) * 128 + sc2) ^ (((d0 + 3) & 7) << 4))) = (bf16)v3;
      }
    }
  }
#undef PISSUE
}

// ---- output projection: A-images (from attn) @ Wto images + bo -> f32 ------
__global__ __launch_bounds__(256) void k_proj_out(
    const bf16* __restrict__ aimg, const bf16* __restrict__ wimg,
    const float* __restrict__ bias, float* __restrict__ out) {
  __shared__ __align__(16) bf16 AB[2][2][8192];
  const int mb = blockIdx.x, nb = blockIdx.y;
  const int m0 = mb * 128, n0 = nb * 128;
  const int tid = threadIdx.x, lane = tid & 63, w = tid >> 6;
  const int c = lane & 15, g = lane >> 4;
  const int mo = (w >> 1) * 64, no = (w & 1) * 64;
  const char* abase = (const char*)aimg + (size_t)mb * 12 * 16384;
  const char* bbase = (const char*)wimg + (size_t)(3 * 6 + nb) * 12 * 16384;

#define PISSUE(KS, BUF) do {                                               \
    const char* a_ = abase + (size_t)(KS) * 16384;                         \
    const char* b_ = bbase + (size_t)(KS) * 16384;                         \
    _Pragma("unroll") for (int ch = 0; ch < 4; ++ch) {                     \
      int ck = w * 4 + ch;                                                 \
      gld16(a_ + ck * 1024 + lane * 16, (char*)AB[BUF][0] + ck * 1024);    \
      gld16(b_ + ck * 1024 + lane * 16, (char*)AB[BUF][1] + ck * 1024);    \
    }                                                                      \
  } while (0)

  PISSUE(0, 0);
  f32x4 acc[4][4] = {};
  asm volatile("s_waitcnt vmcnt(0)" ::: "memory");
  __syncthreads();
  for (int ks = 0; ks < 12; ++ks) {
    const int cur = ks & 1;
    if (ks < 11) PISSUE(ks + 1, cur ^ 1);
    const char* As = (const char*)AB[cur][0];
    const char* Bs = (const char*)AB[cur][1];
    __builtin_amdgcn_s_setprio(1);
#pragma unroll
    for (int kk = 0; kk < 2; ++kk) {
      bf16x8 av[4], bvf[4];
#pragma unroll
      for (int mf = 0; mf < 4; ++mf)
        av[mf] = *(const bf16x8*)(As + swz((mo + mf * 16 + c) * 128 + kk * 64 + g * 16));
#pragma unroll
      for (int nf = 0; nf < 4; ++nf)
        bvf[nf] = *(const bf16x8*)(Bs + swz((no + nf * 16 + c) * 128 + kk * 64 + g * 16));
#pragma unroll
      for (int mf = 0; mf < 4; ++mf)
#pragma unroll
        for (int nf = 0; nf < 4; ++nf)
          acc[mf][nf] = __builtin_amdgcn_mfma_f32_16x16x32_bf16(bvf[nf], av[mf], acc[mf][nf], 0, 0, 0);
    }
    __builtin_amdgcn_s_setprio(0);
    if (ks < 11) {
      asm volatile("s_waitcnt vmcnt(0)" ::: "memory");
      __syncthreads();
    }
  }
#pragma unroll
  for (int nf = 0; nf < 4; ++nf) {
    int n = n0 + no + nf * 16 + g * 4;
    float4 b4 = *(const float4*)&bias[n];
#pragma unroll
    for (int mf = 0; mf < 4; ++mf) {
      int m = m0 + mo + mf * 16 + c;
      float4 v;
      v.x = acc[mf][nf][0] + b4.x;
      v.y = acc[mf][nf][1] + b4.y;
      v.z = acc[mf][nf][2] + b4.z;
      v.w = acc[mf][nf][3] + b4.w;
      *(float4*)(out + (size_t)m * EMB + n) = v;
    }
  }
#undef PISSUE
}

// ----------------------------- flash attention ------------------------------
// Pre-packed K/V tile images + gld16 double-buffer, compact bias slab, mask
// bits, defer-max, setprio. Output written as A-images for k_proj_out.
__global__ __launch_bounds__(256, 4) void k_attn(
    const bf16* __restrict__ qb, const bf16* __restrict__ gk,
    const bf16* __restrict__ gv, const unsigned long long* __restrict__ mbits,
    const float* __restrict__ bias_tab, bf16* __restrict__ aimg) {
  __shared__ __align__(16) bf16 KV[2][2][4096];  // [buf][K/V][8KB image]
  __shared__ float Bslow[384];                   // bias for rel in [-192,192)
  const int bh = blockIdx.x;
  const int b = bh / NH, h = bh % NH;
  const int t0 = blockIdx.y * 64;
  const int tid = threadIdx.x;
  const int lane = tid & 63, w = tid >> 6;
  const int c = lane & 15, g = lane >> 4;
  const float NEGINF = -__builtin_inff();
  const int tl = w * 16 + c;                   // this lane's t (block-local)

  const char* kimg = (const char*)gk + (size_t)bh * 32 * 8192;
  const char* vimg = (const char*)gv + (size_t)bh * 32 * 8192;

#define ISSUE(IT, BUF) do {                                                  \
    const char* ks_ = kimg + (size_t)(IT) * 8192;                            \
    const char* vs_ = vimg + (size_t)(IT) * 8192;                            \
    _Pragma("unroll") for (int jj = 0; jj < 2; ++jj) {                       \
      int ch = w * 2 + jj;                                                   \
      gld16(ks_ + ch * 1024 + lane * 16, (char*)KV[BUF][0] + ch * 1024);     \
      gld16(vs_ + ch * 1024 + lane * 16, (char*)KV[BUF][1] + ch * 1024);     \
    }                                                                        \
  } while (0)

  ISSUE(0, 0);
  // Q fragments (B operand), loop-invariant
  bf16x8 qf[2];
  {
    const bf16* qp = qb + (size_t)((t0 + tl) * NBATCH + b) * EMB + h * 64 + g * 8;
    qf[0] = *(const bf16x8*)qp;
    qf[1] = *(const bf16x8*)(qp + 32);
  }
  // bias slab: Bslow[j] = btab[j - 192]; lookup idx = rel + 192
  const float* btab = bias_tab + h * NREL + (SEQ - 1);
  for (int j = tid; j < 384; j += 256) Bslow[j] = btab[j - 192];
  const float cpos = btab[SEQ - 1];            // bucket 31 (rel >= 128)
  const float cneg = btab[-(SEQ - 1)];         // bucket 15 (rel <= -128)

  float m_p = -1e30f, l_p = 0.f;
  f32x4 o[4] = {};

  asm volatile("s_waitcnt vmcnt(0)" ::: "memory");
  __syncthreads();

  for (int it = 0; it < SEQ / 64; ++it) {
    const int cur = it & 1;
    if (it < SEQ / 64 - 1) ISSUE(it + 1, cur ^ 1);
    const unsigned long long mb = mbits[b * 32 + it];
    const char* Ks = (const char*)KV[cur][0];
    const char* Vs = (const char*)KV[cur][1];

    // QK^T (swapped): sacc[nf][r] = S_raw[t0+tl][s0 + 32*(nf>>1)+g*8+(nf&1)*4+r]
    f32x4 sacc[4] = {};
    __builtin_amdgcn_s_setprio(1);
#pragma unroll
    for (int kk = 0; kk < 2; ++kk) {
#pragma unroll
      for (int nf = 0; nf < 4; ++nf) {
        bf16x8 kf = *(const bf16x8*)(Ks + swz((nf * 16 + c) * 128 + kk * 64 + g * 16));
        sacc[nf] = __builtin_amdgcn_mfma_f32_16x16x32_bf16(kf, qf[kk], sacc[nf], 0, 0, 0);
      }
    }
    __builtin_amdgcn_s_setprio(0);

    const int s0 = it * 64;
    const int d = s0 - t0;
    const bool slow = (d > -192) && (d < 192);
    const float cb = slow ? 0.f : (d >= 192 ? cpos : cneg);

    float rmax = NEGINF;
    if (slow) {
      const int bidx = d - tl + 192;
#pragma unroll
      for (int nf = 0; nf < 4; ++nf) {
        int sb = 32 * (nf >> 1) + g * 8 + (nf & 1) * 4;
#pragma unroll
        for (int r = 0; r < 4; ++r) sacc[nf][r] += Bslow[bidx + sb + r];
      }
    }
    if (mb) {
#pragma unroll
      for (int nf = 0; nf < 4; ++nf) {
        int sb = 32 * (nf >> 1) + g * 8 + (nf & 1) * 4;
#pragma unroll
        for (int r = 0; r < 4; ++r)
          if ((mb >> (sb + r)) & 1) sacc[nf][r] = NEGINF;
      }
    }
#pragma unroll
    for (int nf = 0; nf < 4; ++nf)
#pragma unroll
      for (int r = 0; r < 4; ++r) rmax = fmaxf(rmax, sacc[nf][r]);
    rmax = fmaxf(rmax, __shfl_xor(rmax, 16, 64));
    rmax = fmaxf(rmax, __shfl_xor(rmax, 32, 64));
    const float rm = rmax + cb;                  // row max in score space

    // defer-max: rescale only when some row grew past m_p + 8
    if (!__all(rm <= m_p + 8.0f)) {
      float m_new = fmaxf(m_p, rm);
      float scl = __expf(m_p - m_new);
      m_p = m_new;
      l_p *= scl;
#pragma unroll
      for (int r = 0; r < 4; ++r) {
        float so = __shfl(scl, g * 4 + r, 64);
#pragma unroll
        for (int nf2 = 0; nf2 < 4; ++nf2) o[nf2][r] *= so;
      }
    }
    const float msh = m_p - cb;
    float rsum = 0.f;
    bf16x8 pa[2];
#pragma unroll
    for (int kk = 0; kk < 2; ++kk)
#pragma unroll
      for (int j = 0; j < 8; ++j) {
        float e = __expf(sacc[2 * kk + (j >> 2)][j & 3] - msh);
        rsum += e;
        pa[kk][j] = (bf16)e;
      }
    rsum += __shfl_xor(rsum, 16, 64);
    rsum += __shfl_xor(rsum, 32, 64);
    l_p += rsum;

    // PV
    __builtin_amdgcn_s_setprio(1);
#pragma unroll
    for (int kk = 0; kk < 2; ++kk) {
#pragma unroll
      for (int nf2 = 0; nf2 < 4; ++nf2) {
        bf16x8 vbf = *(const bf16x8*)(Vs + swz((nf2 * 16 + c) * 128 + kk * 64 + g * 16));
        o[nf2] = __builtin_amdgcn_mfma_f32_16x16x32_bf16(pa[kk], vbf, o[nf2], 0, 0, 0);
      }
    }
    __builtin_amdgcn_s_setprio(0);

    if (it < SEQ / 64 - 1) {
      asm volatile("s_waitcnt vmcnt(0)" ::: "memory");  // tile it+1 landed
      __syncthreads();                                  // buf reuse safety
    }
  }
  // epilogue: write O as A-images for k_proj_out.
  // m = t*2+b, k = h*64+d -> tile ((m>>7)*12 + h), byte swz((m&127)*128 + d*2)
#pragma unroll
  for (int r = 0; r < 4; ++r) {
    float lo = __shfl(l_p, g * 4 + r, 64);
    float inv = 1.0f / lo;
    int t = t0 + w * 16 + g * 4 + r;
    int m = t * NBATCH + b;
    char* base = (char*)aimg + ((size_t)(m >> 7) * 12 + h) * 16384;
    int mr128 = (m & 127) * 128;
#pragma unroll
    for (int nf2 = 0; nf2 < 4; ++nf2) {
      int dd = nf2 * 16 + c;
      *(bf16*)(base + swz(mr128 + dd * 2)) = (bf16)(o[nf2][r] * inv);
    }
  }
#undef ISSUE
}

extern "C" void kernel_launch(void* const* d_in, const int* in_sizes, int n_in,
                              void* d_out, int out_size, void* d_ws, size_t ws_size,
                              hipStream_t stream) {
  const float* query = (const float*)d_in[0];
  const float* key_ = (const float*)d_in[1];
  const float* value = (const float*)d_in[2];
  const unsigned char* kpm = (const unsigned char*)d_in[3];
  const float* Wq = (const float*)d_in[4];
  const float* bq = (const float*)d_in[5];
  const float* Wk = (const float*)d_in[6];
  const float* bk = (const float*)d_in[7];
  const float* Wv = (const float*)d_in[8];
  const float* bv = (const float*)d_in[9];
  const float* Wo = (const float*)d_in[10];
  const float* bo = (const float*)d_in[11];
  const float* rel_bias = (const float*)d_in[12];
  float* out = (float*)d_out;

  char* ws = (char*)d_ws;
  const size_t SZb = (size_t)SEQ * NBATCH * EMB * sizeof(bf16);   // 6.29 MB
  const size_t WIMG = (size_t)4 * 6 * 12 * 16384;                 // 4.72 MB
  bf16* qbb = (bf16*)(ws);                                        // Q rows
  bf16* gkb = (bf16*)(ws + SZb);                                  // K images
  bf16* gvb = (bf16*)(ws + 2 * SZb);                              // V images
  bf16* wimg = (bf16*)(ws + 3 * SZb);                             // W images
  float* bias_tab = (float*)(ws + 3 * SZb + WIMG);                // 196 KB
  unsigned long long* mbits =
      (unsigned long long*)(ws + 3 * SZb + WIMG + 196608);        // 512 B
  bf16* ximg = (bf16*)(ws + 3 * SZb + WIMG + 196608 + 512);       // 18.9 MB
  bf16* aimg = ximg;  // X images dead after k_proj_qkv; reuse for attn output

  k_bias_table<<<16, 256, 0, stream>>>(rel_bias, bias_tab);
  k_maskbits<<<16, 256, 0, stream>>>(kpm, mbits);
  k_cvt_w<<<dim3(6, 12, 4), 256, 0, stream>>>(Wq, Wk, Wv, Wo, wimg);
  k_cvt_x<<<dim3(32, 12, 3), 256, 0, stream>>>(query, key_, value, ximg);
  k_proj_qkv<<<dim3(32, 6, 3), 256, 0, stream>>>(
      ximg, wimg, bq, bk, bv, qbb, gkb, gvb);
  k_attn<<<dim3(NBATCH * NH, SEQ / 64), 256, 0, stream>>>(
      qbb, gkb, gvb, mbits, bias_tab, aimg);
  k_proj_out<<<dim3(32, 6), 256, 0, stream>>>(aimg, wimg, bo, out);
}